// Round 10
// baseline (332.748 us; speedup 1.0000x reference)
//
#include <hip/hip_runtime.h>

typedef unsigned short u16;
typedef short bf16x8 __attribute__((ext_vector_type(8)));
typedef float f32x4 __attribute__((ext_vector_type(4)));

#define NBATCH 8192

__device__ __forceinline__ f32x4 mfma16(bf16x8 a, bf16x8 b, f32x4 c) {
  return __builtin_amdgcn_mfma_f32_16x16x32_bf16(a, b, c, 0, 0, 0);
}
__device__ __forceinline__ u16 f2bf(float f) {
  unsigned int u = __float_as_uint(f);
  return (u16)((u + 0x7FFFu + ((u >> 16) & 1u)) >> 16);
}
__device__ __forceinline__ float bf2f(u16 h) {
  return __uint_as_float(((unsigned int)h) << 16);
}
__device__ __forceinline__ float sigm(float x) {
  return __builtin_amdgcn_rcpf(1.f + __builtin_amdgcn_exp2f(-1.44269504f * x));
}
__device__ __forceinline__ float tanh_(float x) {
  float t = __builtin_amdgcn_exp2f(2.88539008f * x);
  return 1.f - 2.f * __builtin_amdgcn_rcpf(t + 1.f);
}
__device__ __forceinline__ bf16x8 pack8(const float* p) {
  float4 a = *(const float4*)p, b = *(const float4*)(p + 4);
  bf16x8 r;
  r[0] = (short)f2bf(a.x); r[1] = (short)f2bf(a.y);
  r[2] = (short)f2bf(a.z); r[3] = (short)f2bf(a.w);
  r[4] = (short)f2bf(b.x); r[5] = (short)f2bf(b.y);
  r[6] = (short)f2bf(b.z); r[7] = (short)f2bf(b.w);
  return r;
}

// R9 post-mortem: occupancy pinned at 1 block/CU even with 16KB LDS (VGPR
// 128 x 4 waves = exactly the 512-reg pool -> no 2nd workgroup). The real
// per-step cost is __syncthreads' vmcnt(0) drain: it serializes the h0seq
// global prefetch (k_gru1, ~900cyc HBM miss exposed/step) and the h0seq
// store (k_gru0) against the barrier, though neither has an intra-kernel
// consumer. R10: LDS-only barrier (lgkmcnt drain, no vmcnt) + 2-step-ahead
// prefetch in k_gru1 so even HBM-miss latency spans a full step.
__device__ __forceinline__ void step_barrier() {
  __builtin_amdgcn_sched_barrier(0);
  asm volatile("s_waitcnt lgkmcnt(0)" ::: "memory");
  __builtin_amdgcn_s_barrier();
  __builtin_amdgcn_sched_barrier(0);
}

// ---------------- k_gru0: layer-0 recurrence ----------------
// LDS: h0b dbuf 2x4K | x dbuf 2x1K = 10K
#define A_H0B  0
#define A_XB   8192
#define A_LDS  10240

#define GRU0_STEP(RD, WR, T)                                                    \
  {                                                                             \
    if (xact && (T) < 63) {                                                     \
      u16 xh = f2bf(xv);                                                        \
      u16 xl = f2bf(xv - bf2f(xh));                                             \
      char* xw = sm + A_XB + (WR)*1024 + xm*64 + xd*2;                          \
      *(u16*)xw = xh; *(u16*)(xw + 16) = xl; *(u16*)(xw + 32) = xh;             \
      if ((T) < 62) xv = gx[(T) + 2];                                           \
    }                                                                           \
    f32x4 accr = {brzr, brzr, brzr, brzr};                                      \
    f32x4 accz = {brzz, brzz, brzz, brzz};                                      \
    f32x4 acch = {bhn0, bhn0, bhn0, bhn0};                                      \
    f32x4 acci = {bin0, bin0, bin0, bin0};                                      \
    _Pragma("unroll") for (int ki = 0; ki < 4; ++ki) {                          \
      bf16x8 a0 = *(bf16x8*)(sm + A_H0B + (RD)*4096 + arow0 + ad[ki]);          \
      accr = mfma16(a0, wr0[ki], accr);                                         \
      accz = mfma16(a0, wz0[ki], accz);                                         \
      acch = mfma16(a0, wn0[ki], acch);                                         \
    }                                                                           \
    {                                                                           \
      bf16x8 ax0 = *(bf16x8*)(sm + A_XB + (RD)*1024 + xr0);                     \
      accr = mfma16(ax0, wf0a, accr);                                           \
      accz = mfma16(ax0, wf0b, accz);                                           \
      acci = mfma16(ax0, wf0c, acci);                                           \
    }                                                                           \
    if ((T) >= 1) { /* stream h0(T-1) swizzled tile to global, verbatim */      \
      uint2 gv = *(const uint2*)(sm + A_H0B + (RD)*4096 + tid*8);               \
      *(uint2*)(h0seq + (size_t)((T)-1)*2097152 + gofs) = gv;                   \
    }                                                                           \
    _Pragma("unroll") for (int r = 0; r < 4; ++r) {                             \
      float rr = sigm(accr[r]);                                                 \
      float zz = sigm(accz[r]);                                                 \
      float nn = tanh_(__builtin_fmaf(rr, acch[r], acci[r]));                   \
      float h = h0s[r]; h = __builtin_fmaf(zz, h - nn, nn); h0s[r] = h;         \
      *(u16*)(sm + A_H0B + (WR)*4096 + st[r]) = f2bf(h);                        \
    }                                                                           \
    step_barrier();                                                             \
  }

__global__ __attribute__((amdgpu_flat_work_group_size(512, 512)))
void k_gru0(const float* __restrict__ x,
            const float* __restrict__ wih0, const float* __restrict__ whh0,
            const float* __restrict__ bih0, const float* __restrict__ bhh0,
            char* __restrict__ h0seq) {
  extern __shared__ char sm[];
  const int tid = threadIdx.x;
  const int wid = tid >> 6;
  const int lane = tid & 63;
  const int lq = lane >> 4;
  const int ul = lane & 15;
  const int u  = wid * 16 + ul;
  const int n0 = blockIdx.x * 16;
  const int sx = (ul & 7) << 4;
  const int gofs = blockIdx.x * 4096 + tid * 8;

  // zero h0b dbuf + x dbuf (10240 B)
  for (int idx = tid; idx < 2560; idx += 512)
    *(float*)(sm + A_H0B + idx * 4) = 0.f;

  // ALL W_hh0 gate rows for unit u in registers (r, z, n)
  bf16x8 wr0[4], wz0[4], wn0[4];
#pragma unroll
  for (int ki = 0; ki < 4; ++ki) {
    wr0[ki] = pack8(whh0 + u * 128 + ki * 32 + lq * 8);
    wz0[ki] = pack8(whh0 + (128 + u) * 128 + ki * 32 + lq * 8);
    wn0[ki] = pack8(whh0 + (256 + u) * 128 + ki * 32 + lq * 8);
  }

  // W_ih0 hi/lo fragments (k0-5: whi for x-hi; k8-13: whi for x-lo; k16-21: wlo)
  bf16x8 wf0a, wf0b, wf0c;
  {
    u16 t0[8] = {0,0,0,0,0,0,0,0}, t1[8] = {0,0,0,0,0,0,0,0}, t2[8] = {0,0,0,0,0,0,0,0};
    u16* ts[3] = {t0, t1, t2};
#pragma unroll
    for (int i = 0; i < 3; ++i) {
      int g = u + 128 * i;
      if (lq < 2) {
        for (int d = 0; d < 6; ++d) ts[i][d] = f2bf(wih0[g * 6 + d]);
      } else if (lq == 2) {
        for (int d = 0; d < 6; ++d) {
          float w = wih0[g * 6 + d];
          u16 h = f2bf(w);
          ts[i][d] = f2bf(w - bf2f(h));
        }
      }
    }
    wf0a = *(bf16x8*)t0; wf0b = *(bf16x8*)t1; wf0c = *(bf16x8*)t2;
  }
  const float brzr = bih0[u] + bhh0[u];
  const float brzz = bih0[u + 128] + bhh0[u + 128];
  const float bin0 = bih0[u + 256], bhn0 = bhh0[u + 256];

  int ad[4];
#pragma unroll
  for (int ki = 0; ki < 4; ++ki) ad[ki] = (ki * 64 + lq * 16) ^ sx;
  const int arow0 = ul * 256;
  const int xr0 = ul * 64 + lq * 16;
  int st[4];
#pragma unroll
  for (int r = 0; r < 4; ++r) {
    int m = lq * 4 + r;
    st[r] = m * 256 + ((u * 2) ^ ((m & 7) << 4));
  }

  float h0s[4];
#pragma unroll
  for (int r = 0; r < 4; ++r) h0s[r] = 0.f;

  // x loaders: 96 threads own one (sample, feature) pair
  const int xm = tid / 6, xd = tid - 6 * xm;
  const bool xact = tid < 96;
  const float* gx = x + (size_t)(n0 + xm) * 384 + xd * 64;

  __syncthreads();  // zeros visible

  float xv = 0.f;
  if (xact) {
    float x0 = gx[0];
    u16 h = f2bf(x0);
    u16 l = f2bf(x0 - bf2f(h));
    char* p = sm + A_XB + xm * 64 + xd * 2;
    *(u16*)p = h; *(u16*)(p + 16) = l; *(u16*)(p + 32) = h;
    xv = gx[1];
  }
  __syncthreads();  // x(0) visible

  for (int t = 0; t < 64; t += 2) {
    GRU0_STEP(0, 1, t)
    GRU0_STEP(1, 0, t + 1)
  }
  // epilogue: h0(63) sits in buf0
  {
    uint2 gv = *(const uint2*)(sm + A_H0B + tid * 8);
    *(uint2*)(h0seq + (size_t)63 * 2097152 + gofs) = gv;
  }
}

// ---------------- k_gru1: layer-1 recurrence ----------------
// LDS: h0in dbuf 2x4K | h1b dbuf 2x4K = 16K. 1 barrier/step.
// 2-step-ahead global prefetch: pend register holds h0(T+1); at step T we
// issue the load of h0(T+2) and write pend into buf[WR].
#define B_H0IN 0
#define B_H1B  8192
#define B_LDS  16384

#define GRU1_STEP(RD, WR, T)                                                    \
  {                                                                             \
    uint2 hvnew = {0u, 0u};                                                     \
    if ((T) < 62) hvnew = *(const uint2*)(gsrc + (size_t)((T)+2)*2097152);      \
    f32x4 accr = {brzr, brzr, brzr, brzr};                                      \
    f32x4 accz = {brzz, brzz, brzz, brzz};                                      \
    f32x4 acci = {bin1, bin1, bin1, bin1};                                      \
    f32x4 acch = {bhn1, bhn1, bhn1, bhn1};                                      \
    _Pragma("unroll") for (int ki = 0; ki < 4; ++ki) {                          \
      bf16x8 p0 = *(bf16x8*)(sm + B_H0IN + (RD)*4096 + arow0 + ad[ki]);         \
      bf16x8 q0 = *(bf16x8*)(sm + B_H1B + (RD)*4096 + arow0 + ad[ki]);          \
      accr = mfma16(p0, wih1f[0][ki], accr);                                    \
      accr = mfma16(q0, wr1[ki], accr);                                         \
      accz = mfma16(p0, wih1f[1][ki], accz);                                    \
      accz = mfma16(q0, wz1[ki], accz);                                         \
      acci = mfma16(p0, wih1f[2][ki], acci);                                    \
      acch = mfma16(q0, wn1[ki], acch);                                         \
    }                                                                           \
    if ((T) < 63) *(uint2*)(sm + B_H0IN + (WR)*4096 + tid*8) = pend;            \
    _Pragma("unroll") for (int r = 0; r < 4; ++r) {                             \
      float rr = sigm(accr[r]);                                                 \
      float zz = sigm(accz[r]);                                                 \
      float nn = tanh_(__builtin_fmaf(rr, acch[r], acci[r]));                   \
      float h = h1s[r]; h = __builtin_fmaf(zz, h - nn, nn); h1s[r] = h;         \
      *(u16*)(sm + B_H1B + (WR)*4096 + st[r]) = f2bf(h);                        \
    }                                                                           \
    step_barrier();                                                             \
    pend = hvnew;                                                               \
  }

__global__ __attribute__((amdgpu_flat_work_group_size(512, 512)))
void k_gru1(const float* __restrict__ wih1, const float* __restrict__ whh1,
            const float* __restrict__ bih1, const float* __restrict__ bhh1,
            const char* __restrict__ h0seq, float* __restrict__ hraw) {
  extern __shared__ char sm[];
  const int tid = threadIdx.x;
  const int wid = tid >> 6;
  const int lane = tid & 63;
  const int lq = lane >> 4;
  const int ul = lane & 15;
  const int u  = wid * 16 + ul;
  const int n0 = blockIdx.x * 16;
  const int sx = (ul & 7) << 4;
  const char* gsrc = h0seq + blockIdx.x * 4096 + tid * 8;

  // zero h1b buf0 (read at t=0)
  for (int idx = tid; idx < 1024; idx += 512)
    *(float*)(sm + B_H1B + idx * 4) = 0.f;
  // h0(0) into h0in buf0 (verbatim copy of k_gru0's swizzled tile)
  {
    uint2 h0v = *(const uint2*)(gsrc);
    *(uint2*)(sm + B_H0IN + tid * 8) = h0v;
  }
  // pend = h0(1), consumed at step 0's LDS write
  uint2 pend = *(const uint2*)(gsrc + 2097152);

  // ALL weights in registers: W_ih1 rows {u,u+128,u+256}; W_hh1 rows {u,u+128,u+256}
  bf16x8 wih1f[3][4], wr1[4], wz1[4], wn1[4];
#pragma unroll
  for (int i = 0; i < 3; ++i) {
    int g = u + 128 * i;
#pragma unroll
    for (int ki = 0; ki < 4; ++ki)
      wih1f[i][ki] = pack8(wih1 + g * 128 + ki * 32 + lq * 8);
  }
#pragma unroll
  for (int ki = 0; ki < 4; ++ki) {
    wr1[ki] = pack8(whh1 + u * 128 + ki * 32 + lq * 8);
    wz1[ki] = pack8(whh1 + (128 + u) * 128 + ki * 32 + lq * 8);
    wn1[ki] = pack8(whh1 + (256 + u) * 128 + ki * 32 + lq * 8);
  }

  const float brzr = bih1[u] + bhh1[u];
  const float brzz = bih1[u + 128] + bhh1[u + 128];
  const float bin1 = bih1[u + 256], bhn1 = bhh1[u + 256];

  int ad[4];
#pragma unroll
  for (int ki = 0; ki < 4; ++ki) ad[ki] = (ki * 64 + lq * 16) ^ sx;
  const int arow0 = ul * 256;
  int st[4];
#pragma unroll
  for (int r = 0; r < 4; ++r) {
    int m = lq * 4 + r;
    st[r] = m * 256 + ((u * 2) ^ ((m & 7) << 4));
  }

  float h1s[4];
#pragma unroll
  for (int r = 0; r < 4; ++r) h1s[r] = 0.f;

  __syncthreads();  // staging visible

  for (int t = 0; t < 64; t += 2) {
    GRU1_STEP(0, 1, t)
    GRU1_STEP(1, 0, t + 1)
  }

#pragma unroll
  for (int r = 0; r < 4; ++r) {
    int m = lq * 4 + r;
    hraw[(size_t)(n0 + m) * 128 + u] = h1s[r];
  }
}

// ------------------------- BN1 partials (coalesced) -------------------------
__global__ void k_bn1p(const float* __restrict__ hraw, float* __restrict__ p) {
  __shared__ float s0[256], s1[256];
  int tid = threadIdx.x, b = blockIdx.x;
  int f = tid & 127, r = tid >> 7;
  float s = 0.f, q = 0.f;
  for (int n = b * 64 + r; n < b * 64 + 64; n += 2) {
    float v = hraw[(size_t)n * 128 + f];
    s += v; q += v * v;
  }
  s0[tid] = s; s1[tid] = q;
  __syncthreads();
  if (tid < 128) {
    p[b * 256 + tid] = s0[tid] + s0[tid + 128];
    p[b * 256 + 128 + tid] = s1[tid] + s1[tid + 128];
  }
}

__global__ void k_bn1r(const float* __restrict__ p, float* __restrict__ mu1,
                       float* __restrict__ rs1) {
  int f = threadIdx.x;
  float s = 0.f, q = 0.f;
  for (int b = 0; b < 128; ++b) { s += p[b * 256 + f]; q += p[b * 256 + 128 + f]; }
  float mu = s / 8192.f, var = q / 8192.f - mu * mu;
  mu1[f] = mu; rs1[f] = rsqrtf(var + 1e-5f);
}

// ------------------------- BN1 apply + row means + Gram/mh partials -------------------------
__global__ void k_attp(const float* __restrict__ hraw, const float* __restrict__ mu1,
                       const float* __restrict__ rs1, const float* __restrict__ g1,
                       const float* __restrict__ b1, float* __restrict__ hidden,
                       float* __restrict__ mvec, float* __restrict__ gpart,
                       float* __restrict__ mhpart) {
  __shared__ float hid[64][128];
  __shared__ float mld[64];
  int tid = threadIdx.x, blk = blockIdx.x, n0 = blk * 64;
  for (int idx = tid; idx < 64 * 128; idx += 256) {
    int n = idx >> 7, f = idx & 127;
    float v = (hraw[(size_t)(n0 + n) * 128 + f] - mu1[f]) * rs1[f] * g1[f] + b1[f];
    hid[n][f] = v;
    hidden[(size_t)(n0 + n) * 128 + f] = v;
  }
  __syncthreads();
  if (tid < 64) {
    float s = 0.f;
    for (int f = 0; f < 128; ++f) s += hid[tid][f];
    s *= (1.f / 128.f);
    mld[tid] = s; mvec[n0 + tid] = s;
  }
  __syncthreads();
  int i = tid >> 1, j0 = (tid & 1) * 64;
  float acc[64];
#pragma unroll
  for (int j = 0; j < 64; ++j) acc[j] = 0.f;
  for (int n = 0; n < 64; ++n) {
    float a = hid[n][i];
#pragma unroll
    for (int j = 0; j < 64; ++j) acc[j] += a * hid[n][j0 + j];
  }
#pragma unroll
  for (int j = 0; j < 64; ++j) gpart[(size_t)blk * 16384 + i * 128 + j0 + j] = acc[j];
  if (tid < 128) {
    float s = 0.f;
    for (int n = 0; n < 64; ++n) s += mld[n] * hid[n][tid];
    mhpart[blk * 128 + tid] = s;
  }
}

// ------------------------- reduce Gram/mh partials -------------------------
__global__ void k_attfa(const float* __restrict__ gpart, const float* __restrict__ mhpart,
                        float* __restrict__ gfull, float* __restrict__ mhfull) {
  int idx = blockIdx.x * 256 + threadIdx.x;
  float s = 0.f;
  for (int b = 0; b < 128; ++b) s += gpart[(size_t)b * 16384 + idx];
  gfull[idx] = s;
  if (blockIdx.x == 0 && threadIdx.x < 128) {
    float t = 0.f;
    for (int b = 0; b < 128; ++b) t += mhpart[b * 128 + threadIdx.x];
    mhfull[threadIdx.x] = t;
  }
}

// ------------------------- M2 = (G/H) @ fc_w^T ; u = mh @ fc_w^T -------------------------
__global__ void k_attfb(const float* __restrict__ gfull, const float* __restrict__ mhfull,
                        const float* __restrict__ fcw, float* __restrict__ m2,
                        float* __restrict__ uvec) {
  int idx = blockIdx.x * 128 + threadIdx.x;
  int k = idx >> 7, j = idx & 127;
  const float4* ga = (const float4*)(gfull + k * 128);
  const float4* fb = (const float4*)(fcw + j * 128);
  float a0 = 0.f, a1 = 0.f, a2 = 0.f, a3 = 0.f;
#pragma unroll 8
  for (int f = 0; f < 32; ++f) {
    float4 a = ga[f], b = fb[f];
    a0 += a.x * b.x; a1 += a.y * b.y; a2 += a.z * b.z; a3 += a.w * b.w;
  }
  m2[idx] = (a0 + a1 + a2 + a3) * (1.f / 128.f);
  if (idx < 128) {
    float s = 0.f;
    const float* fr = fcw + idx * 128;
#pragma unroll 8
    for (int f = 0; f < 128; ++f) s += mhfull[f] * fr[f];
    uvec[idx] = s;
  }
}

// ------------------------- out2 = hidden@M2 - m*u + fc_b ; BN2 partials -------------------------
__global__ void k_out2(const float* __restrict__ hidden, const float* __restrict__ mvec,
                       const float* __restrict__ m2g, const float* __restrict__ uvec,
                       const float* __restrict__ fcb, float* __restrict__ out2,
                       float* __restrict__ bn2p) {
  extern __shared__ char smo[];
  float* m2l = (float*)smo;
  float* hl = m2l + 16384;
  float* ml = hl + 4096;
  float* red = ml + 32;
  int tid = threadIdx.x, blk = blockIdx.x, n0 = blk * 32;
  for (int idx = tid; idx < 16384; idx += 256) m2l[idx] = m2g[idx];
  for (int idx = tid; idx < 4096; idx += 256) hl[idx] = hidden[(size_t)n0 * 128 + idx];
  if (tid < 32) ml[tid] = mvec[n0 + tid];
  __syncthreads();
  int j = tid & 127, rg = tid >> 7;
  float uj = uvec[j], bj = fcb[j];
  float s1 = 0.f, s2 = 0.f;
  for (int q = 0; q < 16; ++q) {
    int nl = rg * 16 + q;
    float s = bj - ml[nl] * uj;
    const float* hr = hl + nl * 128;
#pragma unroll 8
    for (int k = 0; k < 128; ++k) s += hr[k] * m2l[k * 128 + j];
    out2[(size_t)(n0 + nl) * 128 + j] = s;
    s1 += s; s2 += s * s;
  }
  red[tid] = s1; red[256 + tid] = s2;
  __syncthreads();
  if (tid < 128) {
    bn2p[blk * 256 + tid] = red[tid] + red[128 + tid];
    bn2p[blk * 256 + 128 + tid] = red[256 + tid] + red[384 + tid];
  }
}

// ------------------------- BN2 stats -------------------------
__global__ void k_bn2(const float* __restrict__ bn2p, float* __restrict__ mu2,
                      float* __restrict__ rs2) {
  int j = threadIdx.x;
  float s = 0.f, q = 0.f;
  for (int b = 0; b < 256; ++b) {
    s += bn2p[b * 256 + j];
    q += bn2p[b * 256 + 128 + j];
  }
  float mu = s / 8192.f, var = q / 8192.f - mu * mu;
  mu2[j] = mu; rs2[j] = rsqrtf(var + 1e-5f);
}

// ------------------------- BN2 apply + leaky-relu + final GEMV -------------------------
__global__ void k_fin(const float* __restrict__ out2, const float* __restrict__ mu2,
                      const float* __restrict__ rs2, const float* __restrict__ g2,
                      const float* __restrict__ b2, const float* __restrict__ fcow,
                      const float* __restrict__ fcob, float* __restrict__ y) {
  int tid = threadIdx.x, lane = tid & 63, w = tid >> 6;
  int n = blockIdx.x * 4 + w;
  float s = 0.f;
#pragma unroll
  for (int h = 0; h < 2; ++h) {
    int j = lane + h * 64;
    float v = (out2[(size_t)n * 128 + j] - mu2[j]) * rs2[j] * g2[j] + b2[j];
    v = fmaxf(v, 0.01f * v);
    s += v * fcow[j];
  }
  for (int off = 32; off; off >>= 1) s += __shfl_down(s, off);
  if (!lane) y[n] = s + fcob[0];
}

// ------------------------- launch -------------------------
extern "C" void kernel_launch(void* const* d_in, const int* in_sizes, int n_in,
                              void* d_out, int out_size, void* d_ws, size_t ws_size,
                              hipStream_t stream) {
  const float* x    = (const float*)d_in[0];
  const float* wih0 = (const float*)d_in[1];
  const float* whh0 = (const float*)d_in[2];
  const float* bih0 = (const float*)d_in[3];
  const float* bhh0 = (const float*)d_in[4];
  const float* wih1 = (const float*)d_in[5];
  const float* whh1 = (const float*)d_in[6];
  const float* bih1 = (const float*)d_in[7];
  const float* bhh1 = (const float*)d_in[8];
  const float* g1   = (const float*)d_in[9];
  const float* b1   = (const float*)d_in[10];
  const float* fcw  = (const float*)d_in[11];
  const float* fcb  = (const float*)d_in[12];
  const float* g2   = (const float*)d_in[13];
  const float* b2   = (const float*)d_in[14];
  const float* fcow = (const float*)d_in[15];
  const float* fcob = (const float*)d_in[16];

  char* ws = (char*)d_ws;
  float* hraw   = (float*)(ws + 0);
  float* hidden = (float*)(ws + 4194304);
  float* mvec   = (float*)(ws + 8388608);
  float* mu1    = (float*)(ws + 8421376);
  float* rs1    = (float*)(ws + 8421888);
  float* gpart  = (float*)(ws + 8422400);
  float* mhpart = (float*)(ws + 16811008);
  float* m2     = (float*)(ws + 16876544);
  float* uvec   = (float*)(ws + 16942080);
  float* out2   = (float*)(ws + 16942592);
  float* bn2p   = (float*)(ws + 21136896);  // reused: bn1 partials live here first
  float* mu2    = (float*)(ws + 21399040);
  float* rs2    = (float*)(ws + 21399552);
  float* gfull  = (float*)(ws + 21400064);
  float* mhfull = (float*)(ws + 21465600);
  char*  h0seq  = (char*)(ws + 21495808);   // 64 steps x 512 blocks x 4KB = 134217728 B

  (void)hipFuncSetAttribute((const void*)k_out2,
                            hipFuncAttributeMaxDynamicSharedMemorySize, 84096);

  k_gru0<<<512, 512, A_LDS, stream>>>(x, wih0, whh0, bih0, bhh0, h0seq);
  k_gru1<<<512, 512, B_LDS, stream>>>(wih1, whh1, bih1, bhh1, h0seq, hraw);
  k_bn1p<<<128, 256, 0, stream>>>(hraw, bn2p);
  k_bn1r<<<1, 128, 0, stream>>>(bn2p, mu1, rs1);
  k_attp<<<128, 256, 0, stream>>>(hraw, mu1, rs1, g1, b1, hidden, mvec, gpart, mhpart);
  k_attfa<<<64, 256, 0, stream>>>(gpart, mhpart, gfull, mhfull);
  k_attfb<<<128, 128, 0, stream>>>(gfull, mhfull, fcw, m2, uvec);
  k_out2<<<256, 256, 84096, stream>>>(hidden, mvec, m2, uvec, fcb, out2, bn2p);
  k_bn2<<<1, 128, 0, stream>>>(bn2p, mu2, rs2);
  k_fin<<<2048, 256, 0, stream>>>(out2, mu2, rs2, g2, b2, fcow, fcob, (float*)d_out);
}